// Round 6
// baseline (261.541 us; speedup 1.0000x reference)
//
#include <hip/hip_runtime.h>

#define B_ 16
#define N_ 16384
#define C_ 128
#define H_ 512
#define W_ 512
#define L_ 65
#define FG 64

// ws layout (float units)
#define OFF_SUMS 0
#define OFF_CNT  (B_*L_*C_)              // 133120 (ints live here after k_cent)
#define OFF_DIST (OFF_CNT + B_*L_)       // 134160
#define OFF_LAB  (OFF_DIST + B_*L_)      // 135200: B_*N_ ints
#define OFF_BCNT (OFF_LAB + B_*N_)       // 397344: 1024*L_ ints (per-block histograms)

#define APB 512   // points per k_accum block
#define DPB 256   // points per k_dist block (1 per thread)
#define PREP_BLOCKS (B_*N_/256)          // 1024, 64 blocks per image

// fused: zero SUMS/DIST/out + label gather + per-block count histogram (plain store)
__global__ __launch_bounds__(256) void k_prep(const int2* __restrict__ coords,
                                              const int* __restrict__ y,
                                              float* __restrict__ ws,
                                              float* __restrict__ out) {
    __shared__ int s_cnt[L_];
    const int gid = blockIdx.x * 256 + threadIdx.x;   // 0..B*N-1, block within one image
    if (threadIdx.x < L_) s_cnt[threadIdx.x] = 0;
    if (gid < OFF_CNT) ws[gid] = 0.f;                 // zero SUMS (133120 < 262144, covered)
    if (gid < B_ * L_) ws[OFF_DIST + gid] = 0.f;      // zero DIST
    if (gid == 0) out[0] = 0.f;
    __syncthreads();
    const int b = gid >> 14;
    int2 rc = coords[gid];
    int lab = y[(b << 18) + (rc.x << 9) + rc.y];
    ((int*)(ws + OFF_LAB))[gid] = lab;
    atomicAdd(&s_cnt[lab], 1);                        // native ds_add_u32
    __syncthreads();
    if (threadIdx.x < L_)
        ((int*)(ws + OFF_BCNT))[blockIdx.x * L_ + threadIdx.x] = s_cnt[threadIdx.x];
}

// pass 1: segment-sum, NO atomics / NO shfl in inner loop (proven R5 structure).
// wave w owns channels [32w,32w+32); half-wave h uses accumulator copy h.
__global__ __launch_bounds__(256) void k_accum(const float* __restrict__ emb,
                                               float* __restrict__ ws) {
    __shared__ float s_sum[2 * L_ * C_];   // two copies (half-wave parity)
    __shared__ int s_lab[APB];
    const int b = blockIdx.x >> 5;          // 32 blocks per image
    const int base = (blockIdx.x & 31) * APB;
    const int wave = threadIdx.x >> 6;
    const int lane = threadIdx.x & 63;
    const int half = lane >> 5, j = lane & 31;
    const int ch = 32 * wave + j;

    for (int i = threadIdx.x; i < 2 * L_ * C_; i += 256) s_sum[i] = 0.f;
    const int* labg = (const int*)(ws + OFF_LAB) + b * N_ + base;
    for (int i = threadIdx.x; i < APB; i += 256) s_lab[i] = labg[i];
    __syncthreads();

    const float* embp = emb + (size_t)b * N_ * C_ + (size_t)base * C_ + ch;
    float* copy = s_sum + half * (L_ * C_);

    for (int s0 = 0; s0 < APB / 2; s0 += 16) {        // prefetch depth 16
        float e[16]; int lb[16];
        #pragma unroll
        for (int u = 0; u < 16; ++u) {
            int p = 2 * (s0 + u) + half;
            e[u]  = embp[(size_t)p * C_];
            lb[u] = s_lab[p];
        }
        #pragma unroll
        for (int u = 0; u < 16; ++u)
            copy[lb[u] * C_ + ch] += e[u];            // (wave,half)-exclusive cell
    }
    __syncthreads();
    float* gs = ws + OFF_SUMS + b * L_ * C_;
    for (int i = threadIdx.x; i < L_ * C_; i += 256)
        unsafeAtomicAdd(&gs[i], s_sum[i] + s_sum[L_ * C_ + i]);
}

// per image: reduce per-block count histograms -> int counts; divide sums -> centroids
__global__ __launch_bounds__(256) void k_cent(float* __restrict__ ws) {
    __shared__ float s_inv[L_];
    const int b = blockIdx.x;
    const int t = threadIdx.x;
    if (t < L_) {
        const int* bc = (const int*)(ws + OFF_BCNT);
        int c = 0;
        #pragma unroll 8
        for (int k = 0; k < PREP_BLOCKS / B_; ++k)
            c += bc[(b * (PREP_BLOCKS / B_) + k) * L_ + t];
        ((int*)(ws + OFF_CNT))[b * L_ + t] = c;
        s_inv[t] = 1.f / fmaxf((float)c, 1.f);
    }
    __syncthreads();
    float* gs = ws + OFF_SUMS + b * L_ * C_;
    for (int i = t; i < L_ * C_; i += 256) gs[i] *= s_inv[i >> 7];
}

// pass 2: point-per-lane, full 128-ch reduction in registers (proven R5 structure)
__global__ __launch_bounds__(256) void k_dist(const float* __restrict__ emb,
                                              float* __restrict__ ws) {
    __shared__ __align__(16) float4 s_cent4[L_ * 33];  // row stride 33 float4
    __shared__ float s_dist[L_];
    const int b = blockIdx.x >> 6;                      // 64 blocks per image
    const int base = (blockIdx.x & 63) * DPB;

    const float* gcent = ws + OFF_SUMS + b * L_ * C_;
    for (int i = threadIdx.x; i < L_ * 32; i += 256) {
        int l = i >> 5, q = i & 31;
        s_cent4[l * 33 + q] = ((const float4*)gcent)[l * 32 + q];
    }
    if (threadIdx.x < L_) s_dist[threadIdx.x] = 0.f;
    __syncthreads();

    const int p = base + threadIdx.x;                   // this lane's point
    const int lb = ((const int*)(ws + OFF_LAB))[b * N_ + p];
    const float4* ep = (const float4*)(emb + (size_t)b * N_ * C_) + (size_t)p * 32;
    const float4* cp = s_cent4 + lb * 33;
    float acc = 0.f;
    #pragma unroll 8
    for (int q = 0; q < 32; ++q) {
        float4 e = ep[q], c = cp[q];
        float dx = e.x - c.x, dy = e.y - c.y;
        float dz = e.z - c.z, dw = e.w - c.w;
        acc += dx * dx + dy * dy + dz * dz + dw * dw;
    }
    unsafeAtomicAdd(&s_dist[lb], sqrtf(fmaxf(acc, 1e-12f)));
    __syncthreads();
    if (threadIdx.x < L_) {
        float d = s_dist[threadIdx.x];
        if (d != 0.f) unsafeAtomicAdd(ws + OFF_DIST + b * L_ + threadIdx.x, d);
    }
}

#define CSTRIDE 132  // 128 + 4 pad -> conflict-free float4 tile reads

__global__ __launch_bounds__(256) void k_final(float* __restrict__ ws, float* __restrict__ out) {
    __shared__ __align__(16) float s_cc[FG * CSTRIDE];
    __shared__ float s_present[FG];
    __shared__ float s_red[3];  // [0]=pull, [1]=push num, [2]=npairs
    const int b = blockIdx.x;
    const int t = threadIdx.x;

    const float* gcent = ws + OFF_SUMS + b * L_ * C_;
    for (int i = t; i < FG * C_; i += 256) {
        int l = i >> 7, ch = i & 127;
        s_cc[l * CSTRIDE + ch] = gcent[(l + 1) * C_ + ch];
    }
    if (t < 3) s_red[t] = 0.f;
    if (t < FG) {  // exactly wave 0
        int cnt = ((const int*)(ws + OFF_CNT))[b * L_ + 1 + t];
        s_present[t] = (cnt > 0) ? 1.f : 0.f;
        float pl = (cnt > 0) ? ws[OFF_DIST + b * L_ + 1 + t] / (float)cnt : 0.f;
        #pragma unroll
        for (int off = 32; off; off >>= 1) pl += __shfl_xor(pl, off);
        if (t == 0) s_red[0] = pl;
    }
    __syncthreads();

    const int wave = t >> 6, lane = t & 63;
    const int ti = lane >> 3, tj = lane & 7;
    float psum = 0.f, pnp = 0.f;
    for (int tt = wave; tt < 36; tt += 4) {
        int a = 0, c = tt;
        while (c >= 8 - a) { c -= 8 - a; ++a; }
        c += a;  // tile (a, c), a <= c
        int i = a * 8 + ti, jx = c * 8 + tj;
        float acc = 0.f;
        #pragma unroll
        for (int ch = 0; ch < C_; ch += 4) {
            float4 xi = *(const float4*)&s_cc[i * CSTRIDE + ch];
            float4 xj = *(const float4*)&s_cc[jx * CSTRIDE + ch];
            float dx = xi.x - xj.x, dy = xi.y - xj.y;
            float dz = xi.z - xj.z, dw = xi.w - xj.w;
            acc += dx * dx + dy * dy + dz * dz + dw * dw;
        }
        float dm = sqrtf(fmaxf(acc, 1e-12f));
        float pv = fmaxf(1.f - dm, 0.f);           // PUSH_MARGIN = 1
        bool valid = (i < jx) && (s_present[i] > 0.f) && (s_present[jx] > 0.f);
        if (valid) { psum += pv; pnp += 1.f; }
    }
    #pragma unroll
    for (int off = 32; off; off >>= 1) {
        psum += __shfl_xor(psum, off);
        pnp  += __shfl_xor(pnp,  off);
    }
    if (lane == 0) { unsafeAtomicAdd(&s_red[1], psum); unsafeAtomicAdd(&s_red[2], pnp); }
    __syncthreads();
    if (t == 0) {
        float loss = s_red[0] + s_red[1] / fmaxf(s_red[2], 1.f);
        unsafeAtomicAdd(out, loss);
    }
}

extern "C" void kernel_launch(void* const* d_in, const int* in_sizes, int n_in,
                              void* d_out, int out_size, void* d_ws, size_t ws_size,
                              hipStream_t stream) {
    const float* emb   = (const float*)d_in[0];
    const int2* coords = (const int2*)d_in[1];
    const int*  y      = (const int*)d_in[2];
    float* out = (float*)d_out;
    float* ws  = (float*)d_ws;

    k_prep<<<PREP_BLOCKS, 256, 0, stream>>>(coords, y, ws, out);
    k_accum<<<B_ * (N_ / APB), 256, 0, stream>>>(emb, ws);
    k_cent<<<B_, 256, 0, stream>>>(ws);
    k_dist<<<B_ * (N_ / DPB), 256, 0, stream>>>(emb, ws);
    k_final<<<B_, 256, 0, stream>>>(ws, out);
}

// Round 7
// 259.242 us; speedup vs baseline: 1.0089x; 1.0089x over previous
//
#include <hip/hip_runtime.h>

#define B_ 16
#define N_ 16384
#define C_ 128
#define H_ 512
#define W_ 512
#define L_ 65
#define FG 64

// ws layout (float units)
#define OFF_SUMS 0
#define OFF_CNT  (B_*L_*C_)              // 133120 (ints live here after k_cent)
#define OFF_DIST (OFF_CNT + B_*L_)       // 134160
#define OFF_LAB  (OFF_DIST + B_*L_)      // 135200: B_*N_ ints
#define OFF_BCNT (OFF_LAB + B_*N_)       // 397344: 1024*L_ ints (per-block histograms)

#define APB 512   // points per k_accum block
#define DPB 256   // points per k_dist block (1 per thread)
#define PREP_BLOCKS (B_*N_/256)          // 1024, 64 blocks per image

// fused: zero SUMS/DIST/out + label gather + per-block count histogram (plain store)
__global__ __launch_bounds__(256) void k_prep(const int2* __restrict__ coords,
                                              const int* __restrict__ y,
                                              float* __restrict__ ws,
                                              float* __restrict__ out) {
    __shared__ int s_cnt[L_];
    const int gid = blockIdx.x * 256 + threadIdx.x;   // 0..B*N-1, block within one image
    if (threadIdx.x < L_) s_cnt[threadIdx.x] = 0;
    if (gid < OFF_CNT) ws[gid] = 0.f;                 // zero SUMS
    if (gid < B_ * L_) ws[OFF_DIST + gid] = 0.f;      // zero DIST
    if (gid == 0) out[0] = 0.f;
    __syncthreads();
    const int b = gid >> 14;
    int2 rc = coords[gid];
    int lab = y[(b << 18) + (rc.x << 9) + rc.y];
    ((int*)(ws + OFF_LAB))[gid] = lab;
    atomicAdd(&s_cnt[lab], 1);                        // native ds_add_u32
    __syncthreads();
    if (threadIdx.x < L_)
        ((int*)(ws + OFF_BCNT))[blockIdx.x * L_ + threadIdx.x] = s_cnt[threadIdx.x];
}

// pass 1: segment-sum. float4 path: wave covers 2 full point-rows per step
// (1KB coalesced dwordx4), one b128 LDS RMW per step (serial chain /4 vs b32).
// half-wave h uses accumulator copy h (kills lbA==lbB race); lanes within a
// half own disjoint channel quadruples of one row.
__global__ __launch_bounds__(256) void k_accum(const float* __restrict__ emb,
                                               float* __restrict__ ws) {
    __shared__ float4 s_sum4[2 * L_ * 32];   // two copies, plain row layout
    __shared__ int s_lab[APB];
    const int b = blockIdx.x >> 5;            // 32 blocks per image
    const int base = (blockIdx.x & 31) * APB;
    const int wave = threadIdx.x >> 6;
    const int lane = threadIdx.x & 63;
    const int half = lane >> 5, j = lane & 31;

    const float4 zero4 = {0.f, 0.f, 0.f, 0.f};
    for (int i = threadIdx.x; i < 2 * L_ * 32; i += 256) s_sum4[i] = zero4;
    const int* labg = (const int*)(ws + OFF_LAB) + b * N_ + base;
    for (int i = threadIdx.x; i < APB; i += 256) s_lab[i] = labg[i];
    __syncthreads();

    // wave owns 128 consecutive points; 2 points (1KB) per step
    const float4* embp = (const float4*)(emb + (size_t)b * N_ * C_
                                         + (size_t)(base + wave * (APB / 4)) * C_) + j;
    const int* labp = s_lab + wave * (APB / 4);
    float4* copy = s_sum4 + half * (L_ * 32) + j;

    for (int s0 = 0; s0 < APB / 8; s0 += 8) {         // 64 steps, batch 8
        float4 e[8]; int lb[8];
        #pragma unroll
        for (int u = 0; u < 8; ++u) {
            int p = 2 * (s0 + u) + half;              // this half's point
            e[u]  = embp[(size_t)p * 32];             // 16B/lane, 1KB/wave
            lb[u] = labp[p];                          // LDS broadcast (2 addrs/wave)
        }
        #pragma unroll
        for (int u = 0; u < 8; ++u) {                 // b128 RMW, (half)-exclusive copy
            float4 v = copy[lb[u] * 32];
            v.x += e[u].x; v.y += e[u].y; v.z += e[u].z; v.w += e[u].w;
            copy[lb[u] * 32] = v;
        }
    }
    __syncthreads();
    float* gs = ws + OFF_SUMS + b * L_ * C_;
    const float* ss = (const float*)s_sum4;
    for (int i = threadIdx.x; i < L_ * C_; i += 256)
        unsafeAtomicAdd(&gs[i], ss[i] + ss[L_ * C_ + i]);
}

// per image: reduce per-block count histograms -> int counts; divide sums -> centroids
__global__ __launch_bounds__(256) void k_cent(float* __restrict__ ws) {
    __shared__ float s_inv[L_];
    const int b = blockIdx.x;
    const int t = threadIdx.x;
    if (t < L_) {
        const int* bc = (const int*)(ws + OFF_BCNT);
        int c = 0;
        #pragma unroll 8
        for (int k = 0; k < PREP_BLOCKS / B_; ++k)
            c += bc[(b * (PREP_BLOCKS / B_) + k) * L_ + t];
        ((int*)(ws + OFF_CNT))[b * L_ + t] = c;
        s_inv[t] = 1.f / fmaxf((float)c, 1.f);
    }
    __syncthreads();
    float* gs = ws + OFF_SUMS + b * L_ * C_;
    for (int i = t; i < L_ * C_; i += 256) gs[i] *= s_inv[i >> 7];
}

// pass 2: point-per-lane, full 128-ch reduction in registers (proven R5 structure)
__global__ __launch_bounds__(256) void k_dist(const float* __restrict__ emb,
                                              float* __restrict__ ws) {
    __shared__ __align__(16) float4 s_cent4[L_ * 33];  // row stride 33 float4
    __shared__ float s_dist[L_];
    const int b = blockIdx.x >> 6;                      // 64 blocks per image
    const int base = (blockIdx.x & 63) * DPB;

    const float* gcent = ws + OFF_SUMS + b * L_ * C_;
    for (int i = threadIdx.x; i < L_ * 32; i += 256) {
        int l = i >> 5, q = i & 31;
        s_cent4[l * 33 + q] = ((const float4*)gcent)[l * 32 + q];
    }
    if (threadIdx.x < L_) s_dist[threadIdx.x] = 0.f;
    __syncthreads();

    const int p = base + threadIdx.x;                   // this lane's point
    const int lb = ((const int*)(ws + OFF_LAB))[b * N_ + p];
    const float4* ep = (const float4*)(emb + (size_t)b * N_ * C_) + (size_t)p * 32;
    const float4* cp = s_cent4 + lb * 33;
    float acc = 0.f;
    #pragma unroll 8
    for (int q = 0; q < 32; ++q) {
        float4 e = ep[q], c = cp[q];
        float dx = e.x - c.x, dy = e.y - c.y;
        float dz = e.z - c.z, dw = e.w - c.w;
        acc += dx * dx + dy * dy + dz * dz + dw * dw;
    }
    unsafeAtomicAdd(&s_dist[lb], sqrtf(fmaxf(acc, 1e-12f)));
    __syncthreads();
    if (threadIdx.x < L_) {
        float d = s_dist[threadIdx.x];
        if (d != 0.f) unsafeAtomicAdd(ws + OFF_DIST + b * L_ + threadIdx.x, d);
    }
}

#define CSTRIDE 132  // 128 + 4 pad -> conflict-free float4 tile reads

__global__ __launch_bounds__(256) void k_final(float* __restrict__ ws, float* __restrict__ out) {
    __shared__ __align__(16) float s_cc[FG * CSTRIDE];
    __shared__ float s_present[FG];
    __shared__ float s_red[3];  // [0]=pull, [1]=push num, [2]=npairs
    const int b = blockIdx.x;
    const int t = threadIdx.x;

    const float* gcent = ws + OFF_SUMS + b * L_ * C_;
    for (int i = t; i < FG * C_; i += 256) {
        int l = i >> 7, ch = i & 127;
        s_cc[l * CSTRIDE + ch] = gcent[(l + 1) * C_ + ch];
    }
    if (t < 3) s_red[t] = 0.f;
    if (t < FG) {  // exactly wave 0
        int cnt = ((const int*)(ws + OFF_CNT))[b * L_ + 1 + t];
        s_present[t] = (cnt > 0) ? 1.f : 0.f;
        float pl = (cnt > 0) ? ws[OFF_DIST + b * L_ + 1 + t] / (float)cnt : 0.f;
        #pragma unroll
        for (int off = 32; off; off >>= 1) pl += __shfl_xor(pl, off);
        if (t == 0) s_red[0] = pl;
    }
    __syncthreads();

    const int wave = t >> 6, lane = t & 63;
    const int ti = lane >> 3, tj = lane & 7;
    float psum = 0.f, pnp = 0.f;
    for (int tt = wave; tt < 36; tt += 4) {
        int a = 0, c = tt;
        while (c >= 8 - a) { c -= 8 - a; ++a; }
        c += a;  // tile (a, c), a <= c
        int i = a * 8 + ti, jx = c * 8 + tj;
        float acc = 0.f;
        #pragma unroll
        for (int ch = 0; ch < C_; ch += 4) {
            float4 xi = *(const float4*)&s_cc[i * CSTRIDE + ch];
            float4 xj = *(const float4*)&s_cc[jx * CSTRIDE + ch];
            float dx = xi.x - xj.x, dy = xi.y - xj.y;
            float dz = xi.z - xj.z, dw = xi.w - xj.w;
            acc += dx * dx + dy * dy + dz * dz + dw * dw;
        }
        float dm = sqrtf(fmaxf(acc, 1e-12f));
        float pv = fmaxf(1.f - dm, 0.f);           // PUSH_MARGIN = 1
        bool valid = (i < jx) && (s_present[i] > 0.f) && (s_present[jx] > 0.f);
        if (valid) { psum += pv; pnp += 1.f; }
    }
    #pragma unroll
    for (int off = 32; off; off >>= 1) {
        psum += __shfl_xor(psum, off);
        pnp  += __shfl_xor(pnp,  off);
    }
    if (lane == 0) { unsafeAtomicAdd(&s_red[1], psum); unsafeAtomicAdd(&s_red[2], pnp); }
    __syncthreads();
    if (t == 0) {
        float loss = s_red[0] + s_red[1] / fmaxf(s_red[2], 1.f);
        unsafeAtomicAdd(out, loss);
    }
}

extern "C" void kernel_launch(void* const* d_in, const int* in_sizes, int n_in,
                              void* d_out, int out_size, void* d_ws, size_t ws_size,
                              hipStream_t stream) {
    const float* emb   = (const float*)d_in[0];
    const int2* coords = (const int2*)d_in[1];
    const int*  y      = (const int*)d_in[2];
    float* out = (float*)d_out;
    float* ws  = (float*)d_ws;

    k_prep<<<PREP_BLOCKS, 256, 0, stream>>>(coords, y, ws, out);
    k_accum<<<B_ * (N_ / APB), 256, 0, stream>>>(emb, ws);
    k_cent<<<B_, 256, 0, stream>>>(ws);
    k_dist<<<B_ * (N_ / DPB), 256, 0, stream>>>(emb, ws);
    k_final<<<B_, 256, 0, stream>>>(ws, out);
}